// Round 9
// baseline (534.020 us; speedup 1.0000x reference)
//
#include <hip/hip_runtime.h>
#include <hip/hip_bf16.h>
#include <math.h>

typedef __attribute__((ext_vector_type(4))) float f32x4;
typedef __attribute__((ext_vector_type(8))) short s16x8;
typedef __attribute__((ext_vector_type(4))) short s16x4;

#define BB 4
#define TT 2048
#define CC 2048
#define NHEAD 16
#define KVH 4
#define HD 128
#define BT (BB*TT)      // 8192
#define NHC 2048        // N*H
#define KHC 512         // K*H
#define QKVC 3072

__device__ __forceinline__ float bf2f(unsigned short u) {
  union { unsigned u; float f; } v; v.u = ((unsigned)u) << 16; return v.f;
}
__device__ __forceinline__ unsigned short f2bf(float f) {
  union { float f; unsigned u; } v; v.f = f;
  unsigned r = v.u + 0x7fff + ((v.u >> 16) & 1);
  return (unsigned short)(r >> 16);
}
// HW packed f32->bf16 (RTNE), src0 -> low half, src1 -> high half (T12 recipe)
__device__ __forceinline__ unsigned cvt_pk_bf16(float lo, float hi) {
  unsigned r;
  asm("v_cvt_pk_bf16_f32 %0, %1, %2" : "=v"(r) : "v"(lo), "v"(hi));
  return r;
}

#if defined(__has_builtin)
#if __has_builtin(__builtin_amdgcn_exp2f)
#define EXP2F(x) __builtin_amdgcn_exp2f(x)
#endif
#endif
#ifndef EXP2F
#define EXP2F(x) exp2f(x)
#endif

// ---- async global->LDS 16B (lane i lands at ldsbase + i*16; ldsbase must be wave-uniform) ----
__device__ __forceinline__ void glld16(const void* gsrc, void* ldsbase) {
  __builtin_amdgcn_global_load_lds(
      (const __attribute__((address_space(1))) unsigned int*)gsrc,
      (__attribute__((address_space(3))) unsigned int*)(unsigned int)(unsigned long long)ldsbase,
      16, 0, 0);
}

// ---------------- fp32 -> bf16 elementwise ----------------
__global__ void cvt_f2b(const float* __restrict__ in, unsigned short* __restrict__ out, int n4) {
  int i = blockIdx.x * 256 + threadIdx.x;
  if (i >= n4) return;
  float4 v = ((const float4*)in)[i];
  ushort4 o;
  o.x = f2bf(v.x); o.y = f2bf(v.y); o.z = f2bf(v.z); o.w = f2bf(v.w);
  ((ushort4*)out)[i] = o;
}

// ---------------- fp32 [R][Cc] -> bf16 [Cc][R] transpose ----------------
__global__ void trans_f2b(const float* __restrict__ in, unsigned short* __restrict__ out, int R, int Cc) {
  __shared__ float tile[32][33];
  int c0 = blockIdx.x * 32, r0 = blockIdx.y * 32;
  int tx = threadIdx.x, ty = threadIdx.y;
  #pragma unroll
  for (int k = 0; k < 4; k++)
    tile[ty + 8*k][tx] = in[(size_t)(r0 + ty + 8*k) * Cc + c0 + tx];
  __syncthreads();
  #pragma unroll
  for (int k = 0; k < 4; k++)
    out[(size_t)(c0 + ty + 8*k) * R + r0 + tx] = f2bf(tile[tx][ty + 8*k]);
}

// ---------------- V slice transpose bf16 [s][h] -> [h][s'] (PV-fragment-permuted s) ----
// s = g*32 + half*16 + q*4 + rr  ->  s' = g*32 + q*8 + half*4 + rr
// so attn PV reads ONE ds_read_b128 per (su,hb). Verified round 8.
__global__ void trans_v(const unsigned short* __restrict__ qkv, unsigned short* __restrict__ vT) {
  __shared__ unsigned short tile[32][33];
  int slice = blockIdx.z;           // b*4+kh
  int s0 = blockIdx.x * 32, h0 = blockIdx.y * 32;
  int tx = threadIdx.x, ty = threadIdx.y;
  const unsigned short* in = qkv + (size_t)(slice >> 2) * TT * QKVC + (NHC + KHC) + (slice & 3) * HD;
  unsigned short* out = vT + (size_t)slice * HD * TT;
  int txp = ((tx >> 2) & 3) * 8 + ((tx >> 4) & 1) * 4 + (tx & 3);   // permuted s within 32
  #pragma unroll
  for (int k = 0; k < 4; k++)
    tile[ty + 8*k][tx] = in[(size_t)(s0 + ty + 8*k) * QKVC + h0 + tx];
  __syncthreads();
  #pragma unroll
  for (int k = 0; k < 4; k++)
    out[(size_t)(h0 + ty + 8*k) * TT + s0 + txp] = tile[tx][ty + 8*k];
}

// ---------------- RoPE sin/cos table (fp64 precision) ----------------
__global__ void sincos_init(float* __restrict__ stab, float* __restrict__ ctab) {
  int idx = blockIdx.x * 256 + threadIdx.x;
  if (idx >= TT * 64) return;
  int t = idx >> 6, i = idx & 63;
  double inv = exp(-log(10000.0) * ((double)i / 64.0));
  double ang = (double)t * inv;
  stab[idx] = (float)sin(ang);
  ctab[idx] = (float)cos(ang);
}

// ---------------- NT GEMM: 128x128 tile, BK=32, 4 waves, 3 blocks/CU ----------------
// Round-9: revert to the r2-verified m97 structure, but with
// __launch_bounds__(256,3): VGPR capped ~170 -> guaranteed 3 blocks/CU
// (m97's measured occupancy; m114: inter-block wave overlap is the latency
// hiding mechanism — all 1-block/CU 256^2 variants were flat at ~620 TF).
// + XCD-aware flat swizzle (both grids %8==0). Body verbatim from r2.
template<int OUTBF16>
__global__ __launch_bounds__(256, 3) void gemm_nt(
    const unsigned short* __restrict__ A, const unsigned short* __restrict__ Bt,
    void* __restrict__ outp, int M, int Nn, int Kd) {
  __shared__ unsigned short As[128 * 32];
  __shared__ unsigned short Bs[128 * 32];
  int tid = threadIdx.x;
  int wave = tid >> 6, lane = tid & 63, q4 = lane >> 4, l16 = lane & 15;

  int gx = Nn >> 7;
  int nwg = gridDim.x;
  int bid = blockIdx.x;
  int bid2 = (nwg & 7) ? bid : ((bid & 7) * (nwg >> 3) + (bid >> 3));
  int bx = bid2 % gx, by = bid2 / gx;
  int m0 = by * 128, n0 = bx * 128;
  int wm = (wave & 1) * 64, wn = (wave >> 1) * 64;
  f32x4 acc[4][4];
  #pragma unroll
  for (int i = 0; i < 4; i++)
    #pragma unroll
    for (int j = 0; j < 4; j++) acc[i][j] = f32x4{0.f, 0.f, 0.f, 0.f};

  int r0s = wave * 32 + (lane >> 2);
  int r1s = r0s + 16;
  int cg0 = (lane & 3) ^ ((r0s >> 1) & 3);
  int cg1 = (lane & 3) ^ ((r1s >> 1) & 3);
  const unsigned short* Ag0 = A + (size_t)(m0 + r0s) * Kd + cg0 * 8;
  const unsigned short* Ag1 = A + (size_t)(m0 + r1s) * Kd + cg1 * 8;
  const unsigned short* Bg0 = Bt + (size_t)(n0 + r0s) * Kd + cg0 * 8;
  const unsigned short* Bg1 = Bt + (size_t)(n0 + r1s) * Kd + cg1 * 8;
  unsigned short* lA0 = As + (wave * 2 + 0) * 512;
  unsigned short* lA1 = As + (wave * 2 + 1) * 512;
  unsigned short* lB0 = Bs + (wave * 2 + 0) * 512;
  unsigned short* lB1 = Bs + (wave * 2 + 1) * 512;

  int aoff[4], boff[4];
  #pragma unroll
  for (int f = 0; f < 4; f++) {
    int Ra = wm + f * 16 + l16;
    int Rb = wn + f * 16 + l16;
    aoff[f] = Ra * 32 + (q4 ^ ((Ra >> 1) & 3)) * 8;
    boff[f] = Rb * 32 + (q4 ^ ((Rb >> 1) & 3)) * 8;
  }

  for (int k0 = 0; k0 < Kd; k0 += 32) {
    __syncthreads();
    glld16(Ag0 + k0, lA0);
    glld16(Ag1 + k0, lA1);
    glld16(Bg0 + k0, lB0);
    glld16(Bg1 + k0, lB1);
    asm volatile("s_waitcnt vmcnt(0)" ::: "memory");
    __syncthreads();
    s16x8 af[4], bfr[4];
    #pragma unroll
    for (int mf = 0; mf < 4; mf++) af[mf] = *(const s16x8*)&As[aoff[mf]];
    #pragma unroll
    for (int nf = 0; nf < 4; nf++) bfr[nf] = *(const s16x8*)&Bs[boff[nf]];
    #pragma unroll
    for (int mf = 0; mf < 4; mf++)
      #pragma unroll
      for (int nf = 0; nf < 4; nf++)
        acc[mf][nf] = __builtin_amdgcn_mfma_f32_16x16x32_bf16(af[mf], bfr[nf], acc[mf][nf], 0, 0, 0);
  }
  #pragma unroll
  for (int mf = 0; mf < 4; mf++)
    #pragma unroll
    for (int nf = 0; nf < 4; nf++)
      #pragma unroll
      for (int r = 0; r < 4; r++) {
        int row = m0 + wm + mf*16 + q4*4 + r;
        int col = n0 + wn + nf*16 + l16;
        float v = acc[mf][nf][r];
        if (OUTBF16) ((unsigned short*)outp)[(size_t)row * Nn + col] = f2bf(v);
        else         ((float*)outp)[(size_t)row * Nn + col] = v;
      }
}

// ---------------- RMSNorm + RoPE + scale ----------------
// NOTE: q scale folds in log2(e) so attention can use exp2 directly
// (softmax is exactly invariant: p = exp(S-m) = 2^(S*log2e - m*log2e)).
__global__ __launch_bounds__(256) void postproc(
    const unsigned short* __restrict__ qkv, unsigned short* __restrict__ qr,
    unsigned short* __restrict__ kr, const float* __restrict__ stab, const float* __restrict__ ctab) {
  __shared__ float sh[NHC + KHC];
  __shared__ float redq[4], redk[4];
  int row = blockIdx.x;
  int t = row & (TT - 1);
  int tid = threadIdx.x;
  const unsigned short* base = qkv + (size_t)row * QKVC;
  float sq = 0.f, sk = 0.f;
  uint4 qv = *(const uint4*)&base[tid * 8];
  const unsigned short* qp = (const unsigned short*)&qv;
  #pragma unroll
  for (int i = 0; i < 8; i++) { float f = bf2f(qp[i]); sh[tid*8 + i] = f; sq += f*f; }
  unsigned kv = *(const unsigned*)&base[NHC + tid*2];
  {
    float f0 = bf2f((unsigned short)(kv & 0xffff));
    float f1 = bf2f((unsigned short)(kv >> 16));
    sh[NHC + tid*2] = f0; sh[NHC + tid*2 + 1] = f1;
    sk += f0*f0 + f1*f1;
  }
  #pragma unroll
  for (int off = 32; off > 0; off >>= 1) { sq += __shfl_xor(sq, off); sk += __shfl_xor(sk, off); }
  if ((tid & 63) == 0) { redq[tid >> 6] = sq; redk[tid >> 6] = sk; }
  __syncthreads();
  float fq = rsqrtf((redq[0]+redq[1]+redq[2]+redq[3]) * (1.f/NHC) + 1e-6f)
             * (0.08838834764831845f * 1.4426950408889634f);
  float fk = rsqrtf((redk[0]+redk[1]+redk[2]+redk[3]) * (1.f/KHC) + 1e-6f);
  #pragma unroll
  for (int pi = 0; pi < 4; pi++) {
    int P = pi * 256 + tid;
    int head = P >> 6, i = P & 63;
    float s = stab[t*64 + i], c = ctab[t*64 + i];
    float x1 = sh[head*128 + i], x2 = sh[head*128 + i + 64];
    qr[(size_t)row * NHC + head*128 + i]      = f2bf((x1*c - x2*s) * fq);
    qr[(size_t)row * NHC + head*128 + i + 64] = f2bf((x2*c + x1*s) * fq);
  }
  {
    int head = tid >> 6, i = tid & 63;
    float s = stab[t*64 + i], c = ctab[t*64 + i];
    float x1 = sh[NHC + head*128 + i], x2 = sh[NHC + head*128 + i + 64];
    kr[(size_t)row * KHC + head*128 + i]      = f2bf((x1*c - x2*s) * fk);
    kr[(size_t)row * KHC + head*128 + i + 64] = f2bf((x2*c + x1*s) * fk);
  }
}

// ---------------- flash attention v6 (unchanged from r8; 176.5us verified) ----------------
__global__ __launch_bounds__(256, 2) void attn(
    const unsigned short* __restrict__ qr, const unsigned short* __restrict__ kr,
    const unsigned short* __restrict__ vT, unsigned short* __restrict__ enc) {
  __shared__ unsigned short Ks[2][64 * 128];   // 16KB each; Ks[0]+Ks[1] holds Q in prologue
  __shared__ unsigned short Vs[2][128 * 64];   // 16KB each, layout [h][s'-chunk] (permuted s)
  int tid = threadIdx.x;
  int wave = tid >> 6, lane = tid & 63, q4 = lane >> 4, l16 = lane & 15;
  int bid = blockIdx.x;
  int qt = bid & 15, n = (bid >> 4) & 15, b = bid >> 8, kh = n >> 2;

  const unsigned short* kbase = kr + ((size_t)(b * TT)) * KHC + kh * HD;
  const unsigned short* vbase = vT + ((size_t)((b * KVH + kh) * HD)) * TT;

  auto stageK = [&](int j, int kb) {
    const unsigned short* base = kbase + (size_t)(j * 64) * KHC;
    #pragma unroll
    for (int t = 0; t < 4; t++) {
      int L = wave * 4 + t;
      int r = L * 4 + (lane >> 4);
      int cg = (lane & 15) ^ (r & 7);
      glld16(base + (size_t)r * KHC + cg * 8, &Ks[kb][L * 512]);
    }
  };
  auto stageV = [&](int j, int vb) {
    const unsigned short* base = vbase + j * 64;
    #pragma unroll
    for (int t = 0; t < 4; t++) {
      int L = wave * 4 + t;
      int r = L * 8 + (lane >> 3);
      int cg = (lane & 7) ^ (r & 7);
      glld16(base + (size_t)r * TT + cg * 8, &Vs[vb][L * 512]);
    }
  };

  {
    const unsigned short* base = qr + ((size_t)(b * TT + qt * 128)) * NHC + n * HD;
    #pragma unroll
    for (int t = 0; t < 8; t++) {
      int L = wave * 8 + t;
      int r = L * 4 + (lane >> 4);
      int cg = (lane & 15) ^ (r & 7);
      glld16(base + (size_t)r * NHC + cg * 8, (unsigned short*)Ks + L * 512);
    }
  }
  stageV(0, 0);
  asm volatile("s_waitcnt vmcnt(0)" ::: "memory");
  __syncthreads();
  s16x8 qf[2][4];
  #pragma unroll
  for (int qb = 0; qb < 2; qb++)
    #pragma unroll
    for (int ku = 0; ku < 4; ku++) {
      int r = wave * 32 + qb * 16 + l16;
      qf[qb][ku] = *(const s16x8*)&((const unsigned short*)Ks)[r * 128 + (((ku * 4 + q4) ^ (r & 7)) << 3)];
    }
  __syncthreads();
  stageK(0, 0);
  asm volatile("s_waitcnt vmcnt(0)" ::: "memory");
  __syncthreads();

  float m_st[2] = {-1e30f, -1e30f}, l_st[2] = {0.f, 0.f};
  f32x4 O[2][8];
  #pragma unroll
  for (int qb = 0; qb < 2; qb++)
    #pragma unroll
    for (int hb = 0; hb < 8; hb++) O[qb][hb] = f32x4{0.f, 0.f, 0.f, 0.f};

  for (int j = 0; j < 32; j++) {
    int cur = j & 1;
    if (j < 31) { stageK(j + 1, cur ^ 1); stageV(j + 1, cur ^ 1); }
    f32x4 S[2][4];
    #pragma unroll
    for (int qb = 0; qb < 2; qb++)
      #pragma unroll
      for (int mb = 0; mb < 4; mb++) S[qb][mb] = f32x4{0.f, 0.f, 0.f, 0.f};
    __builtin_amdgcn_s_setprio(1);
    #pragma unroll
    for (int mb = 0; mb < 4; mb++) {
      int r = mb * 16 + l16;
      #pragma unroll
      for (int ku = 0; ku < 4; ku++) {
        s16x8 kf = *(const s16x8*)&Ks[cur][r * 128 + (((ku * 4 + q4) ^ (r & 7)) << 3)];
        S[0][mb] = __builtin_amdgcn_mfma_f32_16x16x32_bf16(kf, qf[0][ku], S[0][mb], 0, 0, 0);
        S[1][mb] = __builtin_amdgcn_mfma_f32_16x16x32_bf16(kf, qf[1][ku], S[1][mb], 0, 0, 0);
      }
    }
    __builtin_amdgcn_s_setprio(0);
    s16x8 pf8[2][2];
    #pragma unroll
    for (int qb = 0; qb < 2; qb++) {
      float mx = -1e30f;
      #pragma unroll
      for (int mb = 0; mb < 4; mb++)
        #pragma unroll
        for (int r = 0; r < 4; r++) mx = fmaxf(mx, S[qb][mb][r]);
      mx = fmaxf(mx, __shfl_xor(mx, 16));
      mx = fmaxf(mx, __shfl_xor(mx, 32));
      if (!__all(mx - m_st[qb] <= 8.f)) {
        float alpha = EXP2F(m_st[qb] - mx);
        m_st[qb] = mx;
        l_st[qb] *= alpha;
        #pragma unroll
        for (int hb = 0; hb < 8; hb++) O[qb][hb] *= alpha;
      }
      float mcur = m_st[qb];
      float rs = 0.f;
      #pragma unroll
      for (int su = 0; su < 2; su++) {
        union { s16x8 v; unsigned d[4]; } pu;
        #pragma unroll
        for (int hf = 0; hf < 2; hf++) {
          int mb = su * 2 + hf;
          float p0 = EXP2F(S[qb][mb][0] - mcur);
          float p1 = EXP2F(S[qb][mb][1] - mcur);
          float p2 = EXP2F(S[qb][mb][2] - mcur);
          float p3 = EXP2F(S[qb][mb][3] - mcur);
          rs += (p0 + p1) + (p2 + p3);
          pu.d[hf * 2 + 0] = cvt_pk_bf16(p0, p1);
          pu.d[hf * 2 + 1] = cvt_pk_bf16(p2, p3);
        }
        pf8[qb][su] = pu.v;
      }
      rs += __shfl_xor(rs, 16);
      rs += __shfl_xor(rs, 32);
      l_st[qb] += rs;
    }
    // ---- PV: single b128 per (su,hb) thanks to permuted V layout ----
    __builtin_amdgcn_s_setprio(1);
    #pragma unroll
    for (int su = 0; su < 2; su++) {
      #pragma unroll
      for (int hb = 0; hb < 8; hb++) {
        int r = hb * 16 + l16;
        s16x8 vf = *(const s16x8*)&Vs[cur][r * 64 + (((su * 4 + q4) ^ (r & 7)) << 3)];
        O[0][hb] = __builtin_amdgcn_mfma_f32_16x16x32_bf16(vf, pf8[0][su], O[0][hb], 0, 0, 0);
        O[1][hb] = __builtin_amdgcn_mfma_f32_16x16x32_bf16(vf, pf8[1][su], O[1][hb], 0, 0, 0);
      }
    }
    __builtin_amdgcn_s_setprio(0);
    asm volatile("s_waitcnt vmcnt(0)" ::: "memory");
    __syncthreads();
  }
  #pragma unroll
  for (int qb = 0; qb < 2; qb++) {
    float inv = 1.f / l_st[qb];
    int t = b * TT + qt * 128 + wave * 32 + qb * 16 + l16;
    #pragma unroll
    for (int hb = 0; hb < 8; hb++) {
      union { ushort4 s; unsigned d[2]; } o;
      o.d[0] = cvt_pk_bf16(O[qb][hb][0] * inv, O[qb][hb][1] * inv);
      o.d[1] = cvt_pk_bf16(O[qb][hb][2] * inv, O[qb][hb][3] * inv);
      *(ushort4*)&enc[(size_t)t * NHC + n * HD + hb * 16 + q4 * 4] = o.s;
    }
  }
}

extern "C" void kernel_launch(void* const* d_in, const int* in_sizes, int n_in,
                              void* d_out, int out_size, void* d_ws, size_t ws_size,
                              hipStream_t stream) {
  const float* x  = (const float*)d_in[0];
  const float* Wq = (const float*)d_in[1];
  const float* Wk = (const float*)d_in[2];
  const float* Wv = (const float*)d_in[3];
  const float* Wo = (const float*)d_in[4];
  float* out = (float*)d_out;

  char* ws = (char*)d_ws;
  size_t off = 0;
  auto alloc = [&](size_t bytes) -> void* {
    void* p = ws + off;
    off += (bytes + 255) & ~(size_t)255;
    return p;
  };
  unsigned short* xb    = (unsigned short*)alloc((size_t)BT * CC * 2);
  unsigned short* wqkvt = (unsigned short*)alloc((size_t)QKVC * CC * 2);
  unsigned short* wot   = (unsigned short*)alloc((size_t)CC * NHC * 2);
  unsigned short* qkv   = (unsigned short*)alloc((size_t)BT * QKVC * 2);
  unsigned short* qrb   = (unsigned short*)alloc((size_t)BT * NHC * 2);
  unsigned short* krb   = (unsigned short*)alloc((size_t)BT * KHC * 2);
  unsigned short* vTb   = (unsigned short*)alloc((size_t)BB * KVH * HD * TT * 2);
  unsigned short* encb  = (unsigned short*)alloc((size_t)BT * NHC * 2);
  float* stab = (float*)alloc((size_t)TT * 64 * 4);
  float* ctab = (float*)alloc((size_t)TT * 64 * 4);

  dim3 tb(32, 8);
  cvt_f2b<<<(BT*CC/4 + 255)/256, 256, 0, stream>>>(x, xb, BT*CC/4);
  trans_f2b<<<dim3(NHC/32, CC/32), tb, 0, stream>>>(Wq, wqkvt, CC, NHC);
  trans_f2b<<<dim3(KHC/32, CC/32), tb, 0, stream>>>(Wk, wqkvt + (size_t)NHC*CC, CC, KHC);
  trans_f2b<<<dim3(KHC/32, CC/32), tb, 0, stream>>>(Wv, wqkvt + (size_t)(NHC+KHC)*CC, CC, KHC);
  trans_f2b<<<dim3(NHC/32, NHC/32), tb, 0, stream>>>(Wo, wot, NHC, CC);
  sincos_init<<<(TT*64 + 255)/256, 256, 0, stream>>>(stab, ctab);
  gemm_nt<1><<<(BT/128) * (QKVC/128), 256, 0, stream>>>(xb, wqkvt, qkv, BT, QKVC, CC);
  postproc<<<BT, 256, 0, stream>>>(qkv, qrb, krb, stab, ctab);
  trans_v<<<dim3(TT/32, HD/32, BB*KVH), tb, 0, stream>>>(qkv, vTb);
  attn<<<BB * NHEAD * (TT/128), 256, 0, stream>>>(qrb, krb, vTb, encb);
  gemm_nt<0><<<(BT/128) * (CC/128), 256, 0, stream>>>(encb, wot, out, BT, CC, NHC);
}

// Round 10
// 509.742 us; speedup vs baseline: 1.0476x; 1.0476x over previous
//
#include <hip/hip_runtime.h>
#include <hip/hip_bf16.h>
#include <math.h>

typedef __attribute__((ext_vector_type(4))) float f32x4;
typedef __attribute__((ext_vector_type(16))) float f32x16;
typedef __attribute__((ext_vector_type(8))) short s16x8;
typedef __attribute__((ext_vector_type(4))) short s16x4;

#define BB 4
#define TT 2048
#define CC 2048
#define NHEAD 16
#define KVH 4
#define HD 128
#define BT (BB*TT)      // 8192
#define NHC 2048        // N*H
#define KHC 512         // K*H
#define QKVC 3072

__device__ __forceinline__ float bf2f(unsigned short u) {
  union { unsigned u; float f; } v; v.u = ((unsigned)u) << 16; return v.f;
}
__device__ __forceinline__ unsigned short f2bf(float f) {
  union { float f; unsigned u; } v; v.f = f;
  unsigned r = v.u + 0x7fff + ((v.u >> 16) & 1);
  return (unsigned short)(r >> 16);
}
// HW packed f32->bf16 (RTNE), src0 -> low half, src1 -> high half (T12 recipe)
__device__ __forceinline__ unsigned cvt_pk_bf16(float lo, float hi) {
  unsigned r;
  asm("v_cvt_pk_bf16_f32 %0, %1, %2" : "=v"(r) : "v"(lo), "v"(hi));
  return r;
}

#if defined(__has_builtin)
#if __has_builtin(__builtin_amdgcn_exp2f)
#define EXP2F(x) __builtin_amdgcn_exp2f(x)
#endif
#endif
#ifndef EXP2F
#define EXP2F(x) exp2f(x)
#endif

// ---- async global->LDS 16B (lane i lands at ldsbase + i*16; ldsbase must be wave-uniform) ----
__device__ __forceinline__ void glld16(const void* gsrc, void* ldsbase) {
  __builtin_amdgcn_global_load_lds(
      (const __attribute__((address_space(1))) unsigned int*)gsrc,
      (__attribute__((address_space(3))) unsigned int*)(unsigned int)(unsigned long long)ldsbase,
      16, 0, 0);
}

// ---------------- fp32 -> bf16 elementwise ----------------
__global__ void cvt_f2b(const float* __restrict__ in, unsigned short* __restrict__ out, int n4) {
  int i = blockIdx.x * 256 + threadIdx.x;
  if (i >= n4) return;
  float4 v = ((const float4*)in)[i];
  ushort4 o;
  o.x = f2bf(v.x); o.y = f2bf(v.y); o.z = f2bf(v.z); o.w = f2bf(v.w);
  ((ushort4*)out)[i] = o;
}

// ---------------- ALL weight transposes in one launch (round-10 fusion) ----------------
// All four W matrices have 2048 input rows; blockIdx.x range selects which.
// bx in [0,64): Wq -> wqkvt            (Cc = NHC = 2048)
//    [64,80):  Wk -> wqkvt + NHC*CC    (Cc = KHC = 512)
//    [80,96):  Wv -> wqkvt + (NHC+KHC)*CC
//    [96,160): Wo -> wot               (Cc = CC = 2048)
__global__ void trans_all(const float* __restrict__ Wq, const float* __restrict__ Wk,
                          const float* __restrict__ Wv, const float* __restrict__ Wo,
                          unsigned short* __restrict__ wqkvt, unsigned short* __restrict__ wot) {
  __shared__ float tile[32][33];
  int bx = blockIdx.x, by = blockIdx.y;
  const float* in; unsigned short* out; int Cc;
  if (bx < 64)       { in = Wq; out = wqkvt;                          Cc = NHC; }
  else if (bx < 80)  { in = Wk; out = wqkvt + (size_t)NHC * CC;       Cc = KHC; bx -= 64; }
  else if (bx < 96)  { in = Wv; out = wqkvt + (size_t)(NHC+KHC) * CC; Cc = KHC; bx -= 80; }
  else               { in = Wo; out = wot;                            Cc = CC;  bx -= 96; }
  const int R = 2048;
  int c0 = bx * 32, r0 = by * 32;
  int tx = threadIdx.x, ty = threadIdx.y;
  #pragma unroll
  for (int k = 0; k < 4; k++)
    tile[ty + 8*k][tx] = in[(size_t)(r0 + ty + 8*k) * Cc + c0 + tx];
  __syncthreads();
  #pragma unroll
  for (int k = 0; k < 4; k++)
    out[(size_t)(c0 + ty + 8*k) * R + r0 + tx] = f2bf(tile[tx][ty + 8*k]);
}

// ---------------- V slice transpose bf16 [s][h] -> [h][s'] (PV-fragment-permuted s) ----
// s = g*32 + half*16 + q*4 + rr  ->  s' = g*32 + q*8 + half*4 + rr
// so attn PV reads ONE ds_read_b128 per (su,hb). Verified round 8.
__global__ void trans_v(const unsigned short* __restrict__ qkv, unsigned short* __restrict__ vT) {
  __shared__ unsigned short tile[32][33];
  int slice = blockIdx.z;           // b*4+kh
  int s0 = blockIdx.x * 32, h0 = blockIdx.y * 32;
  int tx = threadIdx.x, ty = threadIdx.y;
  const unsigned short* in = qkv + (size_t)(slice >> 2) * TT * QKVC + (NHC + KHC) + (slice & 3) * HD;
  unsigned short* out = vT + (size_t)slice * HD * TT;
  int txp = ((tx >> 2) & 3) * 8 + ((tx >> 4) & 1) * 4 + (tx & 3);   // permuted s within 32
  #pragma unroll
  for (int k = 0; k < 4; k++)
    tile[ty + 8*k][tx] = in[(size_t)(s0 + ty + 8*k) * QKVC + h0 + tx];
  __syncthreads();
  #pragma unroll
  for (int k = 0; k < 4; k++)
    out[(size_t)(h0 + ty + 8*k) * TT + s0 + txp] = tile[tx][ty + 8*k];
}

// ---------------- RoPE sin/cos table (fp64 precision) ----------------
__global__ void sincos_init(float* __restrict__ stab, float* __restrict__ ctab) {
  int idx = blockIdx.x * 256 + threadIdx.x;
  if (idx >= TT * 64) return;
  int t = idx >> 6, i = idx & 63;
  double inv = exp(-log(10000.0) * ((double)i / 64.0));
  double ang = (double)t * inv;
  stab[idx] = (float)sin(ang);
  ctab[idx] = (float)cos(ang);
}

// ---------------- NT GEMM 256x256, BK=64, 8 waves, 32x32x16 MFMA (verified r7/r8) ----------------
template<int OUTBF16>
__global__ __launch_bounds__(512, 2) void gemm256(
    const unsigned short* __restrict__ A, const unsigned short* __restrict__ Bt,
    void* __restrict__ outp, int M, int Nn, int Kd) {
  __shared__ unsigned short As[2][256 * 64];   // 32 KiB per buf
  __shared__ unsigned short Bs[2][256 * 64];
  int tid = threadIdx.x;
  int wave = tid >> 6, lane = tid & 63;
  int l32 = lane & 31, khf = lane >> 5;

  int gx = Nn >> 8;
  int nwg = gridDim.x;
  int bid = blockIdx.x;
  int bid2 = (nwg & 7) ? bid : ((bid & 7) * (nwg >> 3) + (bid >> 3));
  int bx = bid2 % gx, by = bid2 / gx;
  int m0 = by * 256, n0 = bx * 256;
  int wm = (wave >> 2) * 128, wn = (wave & 3) * 64;   // wave tile 128M x 64N

  f32x16 acc[4][2];
  #pragma unroll
  for (int i = 0; i < 4; i++)
    #pragma unroll
    for (int j = 0; j < 2; j++)
      #pragma unroll
      for (int r = 0; r < 16; r++) acc[i][j][r] = 0.f;

  const unsigned short* Abase = A + (size_t)m0 * Kd;
  const unsigned short* Bbase = Bt + (size_t)n0 * Kd;

  auto stage = [&](const unsigned short* Ak, const unsigned short* Bk, int buf) {
    #pragma unroll
    for (int t = 0; t < 4; t++) {
      int cf = (wave * 4 + t) * 64 + lane;
      int r = cf >> 3, cg = (cf & 7) ^ (r & 7);
      glld16(Ak + (size_t)r * Kd + cg * 8, &As[buf][(wave * 4 + t) * 512]);
    }
    #pragma unroll
    for (int t = 0; t < 4; t++) {
      int cf = (wave * 4 + t) * 64 + lane;
      int r = cf >> 3, cg = (cf & 7) ^ (r & 7);
      glld16(Bk + (size_t)r * Kd + cg * 8, &Bs[buf][(wave * 4 + t) * 512]);
    }
  };

  stage(Abase, Bbase, 0);
  __syncthreads();

  int nkt = Kd >> 6;
  for (int kt = 0; kt < nkt; kt++) {
    int cur = kt & 1;
    if (kt + 1 < nkt) stage(Abase + (kt + 1) * 64, Bbase + (kt + 1) * 64, cur ^ 1);
    #pragma unroll
    for (int ks = 0; ks < 4; ks++) {
      int c = ks * 2 + khf;
      s16x8 af[4], bfv[2];
      #pragma unroll
      for (int mf = 0; mf < 4; mf++) {
        int R = wm + mf * 32 + l32;
        af[mf] = *(const s16x8*)&As[cur][R * 64 + ((c ^ (R & 7)) << 3)];
      }
      #pragma unroll
      for (int nf = 0; nf < 2; nf++) {
        int R = wn + nf * 32 + l32;
        bfv[nf] = *(const s16x8*)&Bs[cur][R * 64 + ((c ^ (R & 7)) << 3)];
      }
      __builtin_amdgcn_s_setprio(1);
      #pragma unroll
      for (int mf = 0; mf < 4; mf++)
        #pragma unroll
        for (int nf = 0; nf < 2; nf++)
          acc[mf][nf] = __builtin_amdgcn_mfma_f32_32x32x16_bf16(af[mf], bfv[nf], acc[mf][nf], 0, 0, 0);
      __builtin_amdgcn_s_setprio(0);
    }
    __syncthreads();
  }

  #pragma unroll
  for (int mf = 0; mf < 4; mf++)
    #pragma unroll
    for (int nf = 0; nf < 2; nf++)
      #pragma unroll
      for (int r = 0; r < 16; r++) {
        int row = m0 + wm + mf * 32 + (r & 3) + 8 * (r >> 2) + 4 * khf;
        int col = n0 + wn + nf * 32 + l32;
        float v = acc[mf][nf][r];
        if (OUTBF16) ((unsigned short*)outp)[(size_t)row * Nn + col] = f2bf(v);
        else         ((float*)outp)[(size_t)row * Nn + col] = v;
      }
}

// ---------------- NT GEMM 256x128 (QKV): perfect grid packing (768 = 3x256), verified r8 ----------------
template<int OUTBF16>
__global__ __launch_bounds__(512, 2) void gemm_qkv(
    const unsigned short* __restrict__ A, const unsigned short* __restrict__ Bt,
    void* __restrict__ outp, int M, int Nn, int Kd) {
  __shared__ unsigned short As[2][256 * 64];   // 32 KiB per buf
  __shared__ unsigned short Bs[2][128 * 64];   // 16 KiB per buf
  int tid = threadIdx.x;
  int wave = tid >> 6, lane = tid & 63;
  int l32 = lane & 31, khf = lane >> 5;

  int gx = Nn >> 7;
  int nwg = gridDim.x;
  int bid = blockIdx.x;
  int bid2 = (nwg & 7) ? bid : ((bid & 7) * (nwg >> 3) + (bid >> 3));
  int bx = bid2 % gx, by = bid2 / gx;
  int m0 = by * 256, n0 = bx * 128;
  int wm = (wave >> 1) * 64, wn = (wave & 1) * 64;   // wave tile 64M x 64N

  f32x16 acc[2][2];
  #pragma unroll
  for (int i = 0; i < 2; i++)
    #pragma unroll
    for (int j = 0; j < 2; j++)
      #pragma unroll
      for (int r = 0; r < 16; r++) acc[i][j][r] = 0.f;

  const unsigned short* Abase = A + (size_t)m0 * Kd;
  const unsigned short* Bbase = Bt + (size_t)n0 * Kd;

  auto stage = [&](const unsigned short* Ak, const unsigned short* Bk, int buf) {
    #pragma unroll
    for (int t = 0; t < 4; t++) {
      int cf = (wave * 4 + t) * 64 + lane;
      int r = cf >> 3, cg = (cf & 7) ^ (r & 7);
      glld16(Ak + (size_t)r * Kd + cg * 8, &As[buf][(wave * 4 + t) * 512]);
    }
    #pragma unroll
    for (int t = 0; t < 2; t++) {
      int cf = (wave * 2 + t) * 64 + lane;
      int r = cf >> 3, cg = (cf & 7) ^ (r & 7);
      glld16(Bk + (size_t)r * Kd + cg * 8, &Bs[buf][(wave * 2 + t) * 512]);
    }
  };

  stage(Abase, Bbase, 0);
  __syncthreads();

  int nkt = Kd >> 6;
  for (int kt = 0; kt < nkt; kt++) {
    int cur = kt & 1;
    if (kt + 1 < nkt) stage(Abase + (kt + 1) * 64, Bbase + (kt + 1) * 64, cur ^ 1);
    #pragma unroll
    for (int ks = 0; ks < 4; ks++) {
      int c = ks * 2 + khf;
      s16x8 af[2], bfv[2];
      #pragma unroll
      for (int mf = 0; mf < 2; mf++) {
        int R = wm + mf * 32 + l32;
        af[mf] = *(const s16x8*)&As[cur][R * 64 + ((c ^ (R & 7)) << 3)];
      }
      #pragma unroll
      for (int nf = 0; nf < 2; nf++) {
        int R = wn + nf * 32 + l32;
        bfv[nf] = *(const s16x8*)&Bs[cur][R * 64 + ((c ^ (R & 7)) << 3)];
      }
      __builtin_amdgcn_s_setprio(1);
      #pragma unroll
      for (int mf = 0; mf < 2; mf++)
        #pragma unroll
        for (int nf = 0; nf < 2; nf++)
          acc[mf][nf] = __builtin_amdgcn_mfma_f32_32x32x16_bf16(af[mf], bfv[nf], acc[mf][nf], 0, 0, 0);
      __builtin_amdgcn_s_setprio(0);
    }
    __syncthreads();
  }

  #pragma unroll
  for (int mf = 0; mf < 2; mf++)
    #pragma unroll
    for (int nf = 0; nf < 2; nf++)
      #pragma unroll
      for (int r = 0; r < 16; r++) {
        int row = m0 + wm + mf * 32 + (r & 3) + 8 * (r >> 2) + 4 * khf;
        int col = n0 + wn + nf * 32 + l32;
        float v = acc[mf][nf][r];
        if (OUTBF16) ((unsigned short*)outp)[(size_t)row * Nn + col] = f2bf(v);
        else         ((float*)outp)[(size_t)row * Nn + col] = v;
      }
}

// ---------------- RMSNorm + RoPE + scale ----------------
// NOTE: q scale folds in log2(e) so attention can use exp2 directly
// (softmax is exactly invariant: p = exp(S-m) = 2^(S*log2e - m*log2e)).
__global__ __launch_bounds__(256) void postproc(
    const unsigned short* __restrict__ qkv, unsigned short* __restrict__ qr,
    unsigned short* __restrict__ kr, const float* __restrict__ stab, const float* __restrict__ ctab) {
  __shared__ float sh[NHC + KHC];
  __shared__ float redq[4], redk[4];
  int row = blockIdx.x;
  int t = row & (TT - 1);
  int tid = threadIdx.x;
  const unsigned short* base = qkv + (size_t)row * QKVC;
  float sq = 0.f, sk = 0.f;
  uint4 qv = *(const uint4*)&base[tid * 8];
  const unsigned short* qp = (const unsigned short*)&qv;
  #pragma unroll
  for (int i = 0; i < 8; i++) { float f = bf2f(qp[i]); sh[tid*8 + i] = f; sq += f*f; }
  unsigned kv = *(const unsigned*)&base[NHC + tid*2];
  {
    float f0 = bf2f((unsigned short)(kv & 0xffff));
    float f1 = bf2f((unsigned short)(kv >> 16));
    sh[NHC + tid*2] = f0; sh[NHC + tid*2 + 1] = f1;
    sk += f0*f0 + f1*f1;
  }
  #pragma unroll
  for (int off = 32; off > 0; off >>= 1) { sq += __shfl_xor(sq, off); sk += __shfl_xor(sk, off); }
  if ((tid & 63) == 0) { redq[tid >> 6] = sq; redk[tid >> 6] = sk; }
  __syncthreads();
  float fq = rsqrtf((redq[0]+redq[1]+redq[2]+redq[3]) * (1.f/NHC) + 1e-6f)
             * (0.08838834764831845f * 1.4426950408889634f);
  float fk = rsqrtf((redk[0]+redk[1]+redk[2]+redk[3]) * (1.f/KHC) + 1e-6f);
  #pragma unroll
  for (int pi = 0; pi < 4; pi++) {
    int P = pi * 256 + tid;
    int head = P >> 6, i = P & 63;
    float s = stab[t*64 + i], c = ctab[t*64 + i];
    float x1 = sh[head*128 + i], x2 = sh[head*128 + i + 64];
    qr[(size_t)row * NHC + head*128 + i]      = f2bf((x1*c - x2*s) * fq);
    qr[(size_t)row * NHC + head*128 + i + 64] = f2bf((x2*c + x1*s) * fq);
  }
  {
    int head = tid >> 6, i = tid & 63;
    float s = stab[t*64 + i], c = ctab[t*64 + i];
    float x1 = sh[NHC + head*128 + i], x2 = sh[NHC + head*128 + i + 64];
    kr[(size_t)row * KHC + head*128 + i]      = f2bf((x1*c - x2*s) * fk);
    kr[(size_t)row * KHC + head*128 + i + 64] = f2bf((x2*c + x1*s) * fk);
  }
}

// ---------------- flash attention v6.1: r8-verified + pairwise-tree max ----------------
__global__ __launch_bounds__(256, 2) void attn(
    const unsigned short* __restrict__ qr, const unsigned short* __restrict__ kr,
    const unsigned short* __restrict__ vT, unsigned short* __restrict__ enc) {
  __shared__ unsigned short Ks[2][64 * 128];   // 16KB each; Ks[0]+Ks[1] holds Q in prologue
  __shared__ unsigned short Vs[2][128 * 64];   // 16KB each, layout [h][s'-chunk] (permuted s)
  int tid = threadIdx.x;
  int wave = tid >> 6, lane = tid & 63, q4 = lane >> 4, l16 = lane & 15;
  int bid = blockIdx.x;
  int qt = bid & 15, n = (bid >> 4) & 15, b = bid >> 8, kh = n >> 2;

  const unsigned short* kbase = kr + ((size_t)(b * TT)) * KHC + kh * HD;
  const unsigned short* vbase = vT + ((size_t)((b * KVH + kh) * HD)) * TT;

  auto stageK = [&](int j, int kb) {
    const unsigned short* base = kbase + (size_t)(j * 64) * KHC;
    #pragma unroll
    for (int t = 0; t < 4; t++) {
      int L = wave * 4 + t;
      int r = L * 4 + (lane >> 4);
      int cg = (lane & 15) ^ (r & 7);
      glld16(base + (size_t)r * KHC + cg * 8, &Ks[kb][L * 512]);
    }
  };
  auto stageV = [&](int j, int vb) {
    const unsigned short* base = vbase + j * 64;
    #pragma unroll
    for (int t = 0; t < 4; t++) {
      int L = wave * 4 + t;
      int r = L * 8 + (lane >> 3);
      int cg = (lane & 7) ^ (r & 7);
      glld16(base + (size_t)r * TT + cg * 8, &Vs[vb][L * 512]);
    }
  };

  {
    const unsigned short* base = qr + ((size_t)(b * TT + qt * 128)) * NHC + n * HD;
    #pragma unroll
    for (int t = 0; t < 8; t++) {
      int L = wave * 8 + t;
      int r = L * 4 + (lane >> 4);
      int cg = (lane & 15) ^ (r & 7);
      glld16(base + (size_t)r * NHC + cg * 8, (unsigned short*)Ks + L * 512);
    }
  }
  stageV(0, 0);
  asm volatile("s_waitcnt vmcnt(0)" ::: "memory");
  __syncthreads();
  s16x8 qf[2][4];
  #pragma unroll
  for (int qb = 0; qb < 2; qb++)
    #pragma unroll
    for (int ku = 0; ku < 4; ku++) {
      int r = wave * 32 + qb * 16 + l16;
      qf[qb][ku] = *(const s16x8*)&((const unsigned short*)Ks)[r * 128 + (((ku * 4 + q4) ^ (r & 7)) << 3)];
    }
  __syncthreads();
  stageK(0, 0);
  asm volatile("s_waitcnt vmcnt(0)" ::: "memory");
  __syncthreads();

  float m_st[2] = {-1e30f, -1e30f}, l_st[2] = {0.f, 0.f};
  f32x4 O[2][8];
  #pragma unroll
  for (int qb = 0; qb < 2; qb++)
    #pragma unroll
    for (int hb = 0; hb < 8; hb++) O[qb][hb] = f32x4{0.f, 0.f, 0.f, 0.f};

  for (int j = 0; j < 32; j++) {
    int cur = j & 1;
    if (j < 31) { stageK(j + 1, cur ^ 1); stageV(j + 1, cur ^ 1); }
    f32x4 S[2][4];
    #pragma unroll
    for (int qb = 0; qb < 2; qb++)
      #pragma unroll
      for (int mb = 0; mb < 4; mb++) S[qb][mb] = f32x4{0.f, 0.f, 0.f, 0.f};
    __builtin_amdgcn_s_setprio(1);
    #pragma unroll
    for (int mb = 0; mb < 4; mb++) {
      int r = mb * 16 + l16;
      #pragma unroll
      for (int ku = 0; ku < 4; ku++) {
        s16x8 kf = *(const s16x8*)&Ks[cur][r * 128 + (((ku * 4 + q4) ^ (r & 7)) << 3)];
        S[0][mb] = __builtin_amdgcn_mfma_f32_16x16x32_bf16(kf, qf[0][ku], S[0][mb], 0, 0, 0);
        S[1][mb] = __builtin_amdgcn_mfma_f32_16x16x32_bf16(kf, qf[1][ku], S[1][mb], 0, 0, 0);
      }
    }
    __builtin_amdgcn_s_setprio(0);
    s16x8 pf8[2][2];
    #pragma unroll
    for (int qb = 0; qb < 2; qb++) {
      // pairwise tree max (depth 3) instead of a 16-deep serial fmax chain
      float t0 = fmaxf(fmaxf(S[qb][0][0], S[qb][0][1]), fmaxf(S[qb][0][2], S[qb][0][3]));
      float t1 = fmaxf(fmaxf(S[qb][1][0], S[qb][1][1]), fmaxf(S[qb][1][2], S[qb][1][3]));
      float t2 = fmaxf(fmaxf(S[qb][2][0], S[qb][2][1]), fmaxf(S[qb][2][2], S[qb][2][3]));
      float t3 = fmaxf(fmaxf(S[qb][3][0], S[qb][3][1]), fmaxf(S[qb][3][2], S[qb][3][3]));
      float mx = fmaxf(fmaxf(t0, t1), fmaxf(t2, t3));
      mx = fmaxf(mx, __shfl_xor(mx, 16));
      mx = fmaxf(mx, __shfl_xor(mx, 32));
      if (!__all(mx - m_st[qb] <= 8.f)) {
        float alpha = EXP2F(m_st[qb] - mx);
        m_st[qb] = mx;
        l_st[qb] *= alpha;
        #pragma unroll
        for (int hb = 0; hb < 8; hb++) O[qb][hb] *= alpha;
      }
      float mcur = m_st[qb];
      float rs = 0.f;
      #pragma unroll
      for (int su = 0; su < 2; su++) {
        union { s16x8 v; unsigned d[4]; } pu;
        #pragma unroll
        for (int hf = 0; hf < 2; hf++) {
          int mb = su * 2 + hf;
          float p0 = EXP2F(S[qb][mb][0] - mcur);
          float p1 = EXP2F(S[qb][mb][1] - mcur);
          float p2 = EXP2F(S[qb][mb][2] - mcur);
          float p3 = EXP2F(S[qb][mb][3] - mcur);
          rs += (p0 + p1) + (p2 + p3);
          pu.d[hf * 2 + 0] = cvt_pk_bf16(p0, p1);
          pu.d[hf * 2 + 1] = cvt_pk_bf16(p2, p3);
        }
        pf8[qb][su] = pu.v;
      }
      rs += __shfl_xor(rs, 16);
      rs += __shfl_xor(rs, 32);
      l_st[qb] += rs;
    }
    // ---- PV: single b128 per (su,hb) thanks to permuted V layout ----
    __builtin_amdgcn_s_setprio(1);
    #pragma unroll
    for (int su = 0; su < 2; su++) {
      #pragma unroll
      for (int hb = 0; hb < 8; hb++) {
        int r = hb * 16 + l16;
        s16x8 vf = *(const s16x8*)&Vs[cur][r * 64 + (((su * 4 + q4) ^ (r & 7)) << 3)];
        O[0][hb] = __builtin_amdgcn_mfma_f32_16x16x32_bf16(vf, pf8[0][su], O[0][hb], 0, 0, 0);
        O[1][hb] = __builtin_amdgcn_mfma_f32_16x16x32_bf16(vf, pf8[1][su], O[1][hb], 0, 0, 0);
      }
    }
    __builtin_amdgcn_s_setprio(0);
    asm volatile("s_waitcnt vmcnt(0)" ::: "memory");
    __syncthreads();
  }
  #pragma unroll
  for (int qb = 0; qb < 2; qb++) {
    float inv = 1.f / l_st[qb];
    int t = b * TT + qt * 128 + wave * 32 + qb * 16 + l16;
    #pragma unroll
    for (int hb = 0; hb < 8; hb++) {
      union { ushort4 s; unsigned d[2]; } o;
      o.d[0] = cvt_pk_bf16(O[qb][hb][0] * inv, O[qb][hb][1] * inv);
      o.d[1] = cvt_pk_bf16(O[qb][hb][2] * inv, O[qb][hb][3] * inv);
      *(ushort4*)&enc[(size_t)t * NHC + n * HD + hb * 16 + q4 * 4] = o.s;
    }
  }
}

extern "C" void kernel_launch(void* const* d_in, const int* in_sizes, int n_in,
                              void* d_out, int out_size, void* d_ws, size_t ws_size,
                              hipStream_t stream) {
  const float* x  = (const float*)d_in[0];
  const float* Wq = (const float*)d_in[1];
  const float* Wk = (const float*)d_in[2];
  const float* Wv = (const float*)d_in[3];
  const float* Wo = (const float*)d_in[4];
  float* out = (float*)d_out;

  char* ws = (char*)d_ws;
  size_t off = 0;
  auto alloc = [&](size_t bytes) -> void* {
    void* p = ws + off;
    off += (bytes + 255) & ~(size_t)255;
    return p;
  };
  unsigned short* xb    = (unsigned short*)alloc((size_t)BT * CC * 2);
  unsigned short* wqkvt = (unsigned short*)alloc((size_t)QKVC * CC * 2);
  unsigned short* wot   = (unsigned short*)alloc((size_t)CC * NHC * 2);
  unsigned short* qkv   = (unsigned short*)alloc((size_t)BT * QKVC * 2);
  unsigned short* qrb   = (unsigned short*)alloc((size_t)BT * NHC * 2);
  unsigned short* krb   = (unsigned short*)alloc((size_t)BT * KHC * 2);
  unsigned short* vTb   = (unsigned short*)alloc((size_t)BB * KVH * HD * TT * 2);
  unsigned short* encb  = (unsigned short*)alloc((size_t)BT * NHC * 2);
  float* stab = (float*)alloc((size_t)TT * 64 * 4);
  float* ctab = (float*)alloc((size_t)TT * 64 * 4);

  dim3 tb(32, 8);
  cvt_f2b<<<(BT*CC/4 + 255)/256, 256, 0, stream>>>(x, xb, BT*CC/4);
  trans_all<<<dim3(160, 64), tb, 0, stream>>>(Wq, Wk, Wv, Wo, wqkvt, wot);
  sincos_init<<<(TT*64 + 255)/256, 256, 0, stream>>>(stab, ctab);
  gemm_qkv<1><<<(BT/256) * (QKVC/128), 512, 0, stream>>>(xb, wqkvt, qkv, BT, QKVC, CC);
  postproc<<<BT, 256, 0, stream>>>(qkv, qrb, krb, stab, ctab);
  trans_v<<<dim3(TT/32, HD/32, BB*KVH), tb, 0, stream>>>(qkv, vTb);
  attn<<<BB * NHEAD * (TT/128), 256, 0, stream>>>(qrb, krb, vTb, encb);
  gemm256<0><<<(BT/256) * (CC/256), 512, 0, stream>>>(encb, wot, out, BT, CC, NHC);
}